// Round 1
// baseline (8876.052 us; speedup 1.0000x reference)
//
#include <hip/hip_runtime.h>
#include <stdint.h>

#define H 1024
#define G_ 256
#define LPAD 128

typedef float  floatx4 __attribute__((ext_vector_type(4)));
typedef short  shortx8 __attribute__((ext_vector_type(8)));

#define MFMA(a, b, c) __builtin_amdgcn_mfma_f32_16x16x32_bf16((a), (b), (c), 0, 0, 0)

__device__ __forceinline__ uint16_t f2bf(float f) {
  union { float f; uint32_t i; } v; v.f = f;
  uint32_t r = (v.i + 0x7FFFu + ((v.i >> 16) & 1u)) >> 16;
  return (uint16_t)r;
}
__device__ __forceinline__ float bf2f(uint16_t u) {
  union { uint32_t i; float f; } v; v.i = ((uint32_t)u) << 16; return v.f;
}
__device__ __forceinline__ float sigmoid_(float x) { return 1.f / (1.f + __expf(-x)); }
__device__ __forceinline__ float tanh_(float x) {
  float ax = fabsf(x);
  float e = __expf(2.f * ax);          // overflow -> inf -> t = 1 (correct limit)
  float t = 1.f - 2.f / (e + 1.f);
  return x >= 0.f ? t : -t;
}

// ---------------- fp32 -> bf16 cast, 8 elems/thread ----------------
__global__ void k_f2b(const float* __restrict__ src, uint16_t* __restrict__ dst) {
  size_t i = ((size_t)blockIdx.x * blockDim.x + threadIdx.x) * 8;
  float4 a = *(const float4*)(src + i);
  float4 b = *(const float4*)(src + i + 4);
  uint16_t o[8] = {f2bf(a.x), f2bf(a.y), f2bf(a.z), f2bf(a.w),
                   f2bf(b.x), f2bf(b.y), f2bf(b.z), f2bf(b.w)};
  uint4 ov; __builtin_memcpy(&ov, o, 16);
  *(uint4*)(dst + i) = ov;
}

// ---------------- setup: start[g] via binary search; zero grid barrier ----------------
__global__ void k_setup(const int* __restrict__ batch, int N, int* __restrict__ start,
                        int* __restrict__ bar) {
  int g = threadIdx.x;
  if (g == 0) *bar = 0;
  if (g > G_) return;
  int lo = 0, hi = N;
  while (lo < hi) { int mid = (lo + hi) >> 1; if (batch[mid] < g) lo = mid + 1; else hi = mid; }
  start[g] = lo;
}

// ---------------- message = relu(h_atom + bias) -> bf16 ----------------
__global__ void k_msg(const float* __restrict__ h_atom, const float* __restrict__ bias,
                      uint16_t* __restrict__ msg) {
  int row = blockIdx.x, t = threadIdx.x;           // 128 threads * 8 elems
  size_t off = (size_t)row * H + t * 8;
  float4 h0 = *(const float4*)(h_atom + off);
  float4 h1 = *(const float4*)(h_atom + off + 4);
  float4 b0 = *(const float4*)(bias + t * 8);
  float4 b1 = *(const float4*)(bias + t * 8 + 4);
  float v[8] = {h0.x + b0.x, h0.y + b0.y, h0.z + b0.z, h0.w + b0.w,
                h1.x + b1.x, h1.y + b1.y, h1.z + b1.z, h1.w + b1.w};
  uint16_t o[8];
#pragma unroll
  for (int i = 0; i < 8; i++) o[i] = f2bf(v[i] > 0.f ? v[i] : 0.f);
  uint4 ov; __builtin_memcpy(&ov, o, 16);
  *(uint4*)(msg + off) = ov;
}

// ---------------- h0 = segment_max(h_atom); write fp32 + bf16, both dirs (buf 0) --------
__global__ void k_h0(const float* __restrict__ h_atom, const int* __restrict__ start,
                     float* __restrict__ hf32, uint16_t* __restrict__ hbf) {
  int g = blockIdx.x, t = threadIdx.x;             // 256 threads * 4 cols
  int s = start[g], e = start[g + 1];
  float m[4] = {-INFINITY, -INFINITY, -INFINITY, -INFINITY};
  const float* base = h_atom + t * 4;
  for (int a = s; a < e; a++) {
    float4 v = *(const float4*)(base + (size_t)a * H);
    m[0] = fmaxf(m[0], v.x); m[1] = fmaxf(m[1], v.y);
    m[2] = fmaxf(m[2], v.z); m[3] = fmaxf(m[3], v.w);
  }
  if (s == e) { m[0] = m[1] = m[2] = m[3] = 0.f; }
#pragma unroll
  for (int i = 0; i < 4; i++) {
    int c = t * 4 + i;
    float mv = m[i];
    uint16_t bv = f2bf(mv);
    // layout: [(dir*2 + buf)][G][H]; buf 0 for both dirs
    hf32[(size_t)0 * G_ * H + (size_t)g * H + c] = mv;
    hf32[(size_t)2 * G_ * H + (size_t)g * H + c] = mv;
    hbf [(size_t)0 * G_ * H + (size_t)g * H + c] = bv;
    hbf [(size_t)2 * G_ * H + (size_t)g * H + c] = bv;
  }
}

// ---------------- xg = msg @ [Wf; Wb]^T  -> (N, 6144) bf16 ----------------
// 128x128 tile, BK=64, 4 waves 2x2, 16x16x32 MFMA, register-staged LDS.
// Epilogue: stage C tile in LDS (reuse As/Bs), then coalesced 16B stores
// (old scalar 2B scatter caused 11x WRITE_SIZE amplification: 2.28GB vs 201MB ideal).
__global__ __launch_bounds__(256) void k_gemm_xg(
    const uint16_t* __restrict__ A, const uint16_t* __restrict__ Wf,
    const uint16_t* __restrict__ Wb, uint16_t* __restrict__ C, int N) {
  __shared__ __align__(16) uint16_t SM[128 * 128];   // As(0..8191) Bs(8192..16383); reused as Cs
  uint16_t* As = SM;
  uint16_t* Bs = SM + 128 * 64;
  int bn = blockIdx.x, bm = blockIdx.y;            // bn 0..47, bm 0..N/128-1
  const uint16_t* B = (bn < 24) ? Wf : Wb;
  int brow = (bn < 24 ? bn : bn - 24) * 128;
  int tid = threadIdx.x, wid = tid >> 6, lane = tid & 63;
  int wm = wid >> 1, wn = wid & 1;
  floatx4 acc[4][4];
#pragma unroll
  for (int mi = 0; mi < 4; mi++)
#pragma unroll
    for (int ni = 0; ni < 4; ni++) acc[mi][ni] = (floatx4){0.f, 0.f, 0.f, 0.f};
  int arow = bm * 128;
  for (int kb = 0; kb < H; kb += 64) {
    uint4 av[4], bv[4];
#pragma unroll
    for (int p = 0; p < 4; p++) {                  // chunk c: row c>>3, k-off (c&7)*8
      int c = p * 256 + tid;
      av[p] = *(const uint4*)(A + (size_t)(arow + (c >> 3)) * H + kb + (c & 7) * 8);
      bv[p] = *(const uint4*)(B + (size_t)(brow + (c >> 3)) * H + kb + (c & 7) * 8);
    }
    __syncthreads();                               // prior iter's LDS reads done
#pragma unroll
    for (int p = 0; p < 4; p++) {
      int c = p * 256 + tid;
      *(uint4*)(As + (size_t)c * 8) = av[p];
      *(uint4*)(Bs + (size_t)c * 8) = bv[p];
    }
    __syncthreads();
#pragma unroll
    for (int ks = 0; ks < 2; ks++) {
      const uint16_t* ab = As + ((wm * 64 + (lane & 15)) * 64 + ks * 32 + (lane >> 4) * 8);
      const uint16_t* bb = Bs + ((wn * 64 + (lane & 15)) * 64 + ks * 32 + (lane >> 4) * 8);
      shortx8 af[4], bfr[4];
#pragma unroll
      for (int i = 0; i < 4; i++) {
        af[i]  = *(const shortx8*)(ab + i * 16 * 64);
        bfr[i] = *(const shortx8*)(bb + i * 16 * 64);
      }
#pragma unroll
      for (int mi = 0; mi < 4; mi++)
#pragma unroll
        for (int ni = 0; ni < 4; ni++)
          acc[mi][ni] = MFMA(af[mi], bfr[ni], acc[mi][ni]);
    }
  }
  __syncthreads();                                 // last MFMA LDS reads done; SM -> Cs
  // C/D layout: col = lane&15, row = (lane>>4)*4 + r  [m89-verified]
  int crow = wm * 64 + (lane >> 4) * 4;
  int ccol = wn * 64 + (lane & 15);
#pragma unroll
  for (int mi = 0; mi < 4; mi++)
#pragma unroll
    for (int ni = 0; ni < 4; ni++)
#pragma unroll
      for (int r = 0; r < 4; r++)
        SM[(crow + mi * 16 + r) * 128 + ccol + ni * 16] = f2bf(acc[mi][ni][r]);
  __syncthreads();
#pragma unroll
  for (int p = 0; p < 8; p++) {                    // 128 rows x 16 uint4/row, coalesced
    int c = p * 256 + tid;
    int row = c >> 4, col = (c & 15) * 8;
    *(uint4*)(C + (size_t)(arow + row) * 6144 + bn * 128 + col) =
        *(const uint4*)(SM + row * 128 + col);
  }
}

// ---------------- persistent fused GRU: all 128 time steps, both directions ----------------
// Cooperative launch, 256 wgs (1/CU). Same per-step body/decomposition as the old k_step;
// a device-scope atomic barrier replaces the 128 kernel launches (kills per-dispatch L2
// invalidate->weight refetch, launch gaps, and downclock on tiny serial kernels).
__global__ __launch_bounds__(256) void k_gru(
    const uint16_t* __restrict__ xg,
    const uint16_t* __restrict__ whf, const uint16_t* __restrict__ whb,
    const float* __restrict__ bihf, const float* __restrict__ bhhf,
    const float* __restrict__ bihb, const float* __restrict__ bhhb,
    float* __restrict__ hf32, uint16_t* __restrict__ hbf,
    const int* __restrict__ start, float* __restrict__ out,
    int* bar) {
  __shared__ __align__(16) uint16_t As[64 * 64];
  __shared__ __align__(16) uint16_t Bs[96 * 64];
  __shared__ float HG[64 * 97];                    // stride 97: gate reads <=2-way banks
  int b = blockIdx.x;
  int e = b & 7, hib = b >> 3;
  int d = e >> 2, jm = e & 3;                      // b&7 -> XCD slot: (dir, j%4) weight affinity
  int jc = (hib & 7) * 4 + jm;                     // 0..31 (32-col chunk within H)
  int g0 = (hib >> 3) * 64;
  const uint16_t* W = d ? whb : whf;
  int tid = threadIdx.x, wid = tid >> 6, lane = tid & 63;
  int wm = wid >> 1, wn = wid & 1;                 // waves 2x2 over (64 x 96) -> 32x48 tiles

  // loop-invariant gate-phase values
  int base = tid * 8;
  int gl = base >> 5, j0 = base & 31;
  int g = g0 + gl;
  int s = start[g], cnt = start[g + 1] - s;
  int col0 = jc * 32 + j0;
  const float* bih = d ? bihb : bihf;
  const float* bhh = d ? bhhb : bhhf;

  for (int l = 0; l < LPAD; l++) {
    int cur = l & 1;
    const uint16_t* hsrc = hbf + (size_t)(d * 2 + cur) * G_ * H;
    floatx4 acc[2][3];
#pragma unroll
    for (int mi = 0; mi < 2; mi++)
#pragma unroll
      for (int ni = 0; ni < 3; ni++) acc[mi][ni] = (floatx4){0.f, 0.f, 0.f, 0.f};

    for (int kb = 0; kb < H; kb += 64) {
      uint4 av[2], bv[3];
#pragma unroll
      for (int p = 0; p < 2; p++) {                // A: 64x64 bf16, 512 chunks
        int c = p * 256 + tid;
        av[p] = *(const uint4*)(hsrc + (size_t)(g0 + (c >> 3)) * H + kb + (c & 7) * 8);
      }
#pragma unroll
      for (int p = 0; p < 3; p++) {                // B: 96x64 bf16 (r,z,n weight rows)
        int c = p * 256 + tid;
        int row = c >> 3;
        int wrow = (row >> 5) * H + jc * 32 + (row & 31);
        bv[p] = *(const uint4*)(W + (size_t)wrow * H + kb + (c & 7) * 8);
      }
      __syncthreads();
#pragma unroll
      for (int p = 0; p < 2; p++) *(uint4*)(As + (size_t)(p * 256 + tid) * 8) = av[p];
#pragma unroll
      for (int p = 0; p < 3; p++) *(uint4*)(Bs + (size_t)(p * 256 + tid) * 8) = bv[p];
      __syncthreads();
#pragma unroll
      for (int ks = 0; ks < 2; ks++) {
        const uint16_t* ab = As + ((wm * 32 + (lane & 15)) * 64 + ks * 32 + (lane >> 4) * 8);
        const uint16_t* bb = Bs + ((wn * 48 + (lane & 15)) * 64 + ks * 32 + (lane >> 4) * 8);
        shortx8 a0 = *(const shortx8*)ab;
        shortx8 a1 = *(const shortx8*)(ab + 16 * 64);
#pragma unroll
        for (int ni = 0; ni < 3; ni++) {
          shortx8 bvf = *(const shortx8*)(bb + ni * 16 * 64);
          acc[0][ni] = MFMA(a0, bvf, acc[0][ni]);
          acc[1][ni] = MFMA(a1, bvf, acc[1][ni]);
        }
      }
    }
    __syncthreads();                               // last MFMA ds_reads done before HG reuse
    // spill hg (64x96) to LDS for the gate-triple exchange
#pragma unroll
    for (int mi = 0; mi < 2; mi++)
#pragma unroll
      for (int ni = 0; ni < 3; ni++) {
        int row0 = wm * 32 + mi * 16 + (lane >> 4) * 4;
        int col = wn * 48 + ni * 16 + (lane & 15);
#pragma unroll
        for (int r = 0; r < 4; r++) HG[(row0 + r) * 97 + col] = acc[mi][ni][r];
      }
    __syncthreads();

    // gates: 64*32 = 2048 h-elems, 8 per thread
    int t = d ? (LPAD - 1 - l) : l;
    bool active = (t < cnt);                       // padded steps: xt = b_ih (msg == 0)
    const uint16_t* xp = xg + (size_t)(s + t) * 6144 + (size_t)d * 3072;  // deref iff active
    const float* h_old = hf32 + ((size_t)(d * 2 + cur) * G_ + g) * H + col0;
    float* h_new32 = hf32 + ((size_t)(d * 2 + (cur ^ 1)) * G_ + g) * H + col0;
    uint16_t* h_newb = hbf + ((size_t)(d * 2 + (cur ^ 1)) * G_ + g) * H + col0;
    float* op = out + (size_t)(s + t) * 2048 + (size_t)d * H + col0;
#pragma unroll
    for (int i = 0; i < 8; i++) {
      int c = col0 + i;
      float hr = HG[gl * 97 + j0 + i];
      float hz = HG[gl * 97 + 32 + j0 + i];
      float hn = HG[gl * 97 + 64 + j0 + i];
      float xr = 0.f, xz = 0.f, xn = 0.f;
      if (active) { xr = bf2f(xp[c]); xz = bf2f(xp[H + c]); xn = bf2f(xp[2 * H + c]); }
      float r = sigmoid_(xr + bih[c] + hr + bhh[c]);
      float z = sigmoid_(xz + bih[H + c] + hz + bhh[H + c]);
      float n = tanh_(xn + bih[2 * H + c] + r * (hn + bhh[2 * H + c]));
      float hv = h_old[i];
      float hnew = (1.f - z) * n + z * hv;
      h_new32[i] = hnew;
      h_newb[i] = f2bf(hnew);
      if (active) op[i] = hnew;
    }

    // ---- grid barrier: all h writes visible before any wg starts step l+1 ----
    __syncthreads();                               // each wave drains its own vmem (vmcnt 0)
    if (tid == 0) {
      __threadfence();                             // release: flush this XCD's dirty L2 lines
      __hip_atomic_fetch_add(bar, 1, __ATOMIC_RELEASE, __HIP_MEMORY_SCOPE_AGENT);
      int tgt = (l + 1) << 8;                      // 256 wgs per step, monotonic counter
      while (__hip_atomic_load(bar, __ATOMIC_RELAXED, __HIP_MEMORY_SCOPE_AGENT) < tgt)
        __builtin_amdgcn_s_sleep(2);
      __threadfence();                             // acquire: invalidate stale lines
    }
    __syncthreads();
  }
}

extern "C" void kernel_launch(void* const* d_in, const int* in_sizes, int n_in,
                              void* d_out, int out_size, void* d_ws, size_t ws_size,
                              hipStream_t stream) {
  const float* h_atom = (const float*)d_in[0];
  const int*   batch  = (const int*)d_in[1];
  const float* bias   = (const float*)d_in[2];
  const float* w_ih_f = (const float*)d_in[3];
  const float* w_hh_f = (const float*)d_in[4];
  const float* b_ih_f = (const float*)d_in[5];
  const float* b_hh_f = (const float*)d_in[6];
  const float* w_ih_b = (const float*)d_in[7];
  const float* w_hh_b = (const float*)d_in[8];
  const float* b_ih_b = (const float*)d_in[9];
  const float* b_hh_b = (const float*)d_in[10];
  int N = in_sizes[0] / H;                          // 16384
  float* out = (float*)d_out;

  const size_t W3 = (size_t)3 * H * H;              // 3.1M elems per weight
  char* ws = (char*)d_ws;
  uint16_t* msg  = (uint16_t*)ws;                           // N*H bf16
  uint16_t* xg   = (uint16_t*)(ws + (size_t)N * H * 2);     // N*6144 bf16
  char* p = ws + (size_t)N * H * 2 + (size_t)N * 6144 * 2;
  uint16_t* wihf = (uint16_t*)p; p += W3 * 2;
  uint16_t* wihb = (uint16_t*)p; p += W3 * 2;
  uint16_t* whhf = (uint16_t*)p; p += W3 * 2;
  uint16_t* whhb = (uint16_t*)p; p += W3 * 2;
  float*    hf32 = (float*)p;    p += (size_t)4 * G_ * H * 4;  // [dir][buf][G][H]
  uint16_t* hbf  = (uint16_t*)p; p += (size_t)4 * G_ * H * 2;
  int*      start = (int*)p;                                   // 257 ints
  int*      bar   = (int*)(p + 2048);                          // grid-barrier counter

  int wgrid = (int)(W3 / (256 * 8));                // 1536
  k_f2b<<<wgrid, 256, 0, stream>>>(w_ih_f, wihf);
  k_f2b<<<wgrid, 256, 0, stream>>>(w_ih_b, wihb);
  k_f2b<<<wgrid, 256, 0, stream>>>(w_hh_f, whhf);
  k_f2b<<<wgrid, 256, 0, stream>>>(w_hh_b, whhb);
  k_setup<<<1, 512, 0, stream>>>(batch, N, start, bar);
  k_msg<<<N, 128, 0, stream>>>(h_atom, bias, msg);
  k_h0<<<G_, 256, 0, stream>>>(h_atom, start, hf32, hbf);
  k_gemm_xg<<<dim3(48, N / 128), 256, 0, stream>>>(msg, wihf, wihb, xg, N);

  void* ka[] = {(void*)&xg, (void*)&whhf, (void*)&whhb,
                (void*)&b_ih_f, (void*)&b_hh_f, (void*)&b_ih_b, (void*)&b_hh_b,
                (void*)&hf32, (void*)&hbf, (void*)&start, (void*)&out, (void*)&bar};
  hipLaunchCooperativeKernel(k_gru, dim3(G_), dim3(256), ka, 0, stream);
}

// Round 3
// 7435.247 us; speedup vs baseline: 1.1938x; 1.1938x over previous
//
#include <hip/hip_runtime.h>
#include <stdint.h>

#define H 1024
#define G_ 256
#define LPAD 128

typedef float  floatx4 __attribute__((ext_vector_type(4)));
typedef short  shortx8 __attribute__((ext_vector_type(8)));

#define MFMA(a, b, c) __builtin_amdgcn_mfma_f32_16x16x32_bf16((a), (b), (c), 0, 0, 0)

__device__ __forceinline__ uint16_t f2bf(float f) {
  union { float f; uint32_t i; } v; v.f = f;
  uint32_t r = (v.i + 0x7FFFu + ((v.i >> 16) & 1u)) >> 16;
  return (uint16_t)r;
}
__device__ __forceinline__ float bf2f(uint16_t u) {
  union { uint32_t i; float f; } v; v.i = ((uint32_t)u) << 16; return v.f;
}
__device__ __forceinline__ float sigmoid_(float x) { return 1.f / (1.f + __expf(-x)); }
__device__ __forceinline__ float tanh_(float x) {
  float ax = fabsf(x);
  float e = __expf(2.f * ax);          // overflow -> inf -> t = 1 (correct limit)
  float t = 1.f - 2.f / (e + 1.f);
  return x >= 0.f ? t : -t;
}

// ---------------- fp32 -> bf16 cast, 8 elems/thread ----------------
__global__ void k_f2b(const float* __restrict__ src, uint16_t* __restrict__ dst) {
  size_t i = ((size_t)blockIdx.x * blockDim.x + threadIdx.x) * 8;
  float4 a = *(const float4*)(src + i);
  float4 b = *(const float4*)(src + i + 4);
  uint16_t o[8] = {f2bf(a.x), f2bf(a.y), f2bf(a.z), f2bf(a.w),
                   f2bf(b.x), f2bf(b.y), f2bf(b.z), f2bf(b.w)};
  uint4 ov; __builtin_memcpy(&ov, o, 16);
  *(uint4*)(dst + i) = ov;
}

// ---------------- setup: start[g] via binary search; zero group barriers ----------------
__global__ void k_setup(const int* __restrict__ batch, int N, int* __restrict__ start,
                        int* __restrict__ bar) {
  int g = threadIdx.x;
  if (g < 512) bar[g] = 0;                         // 8 groups x 32-int stride (+ slack)
  if (g > G_) return;
  int lo = 0, hi = N;
  while (lo < hi) { int mid = (lo + hi) >> 1; if (batch[mid] < g) lo = mid + 1; else hi = mid; }
  start[g] = lo;
}

// ---------------- message = relu(h_atom + bias) -> bf16 ----------------
__global__ void k_msg(const float* __restrict__ h_atom, const float* __restrict__ bias,
                      uint16_t* __restrict__ msg) {
  int row = blockIdx.x, t = threadIdx.x;           // 128 threads * 8 elems
  size_t off = (size_t)row * H + t * 8;
  float4 h0 = *(const float4*)(h_atom + off);
  float4 h1 = *(const float4*)(h_atom + off + 4);
  float4 b0 = *(const float4*)(bias + t * 8);
  float4 b1 = *(const float4*)(bias + t * 8 + 4);
  float v[8] = {h0.x + b0.x, h0.y + b0.y, h0.z + b0.z, h0.w + b0.w,
                h1.x + b1.x, h1.y + b1.y, h1.z + b1.z, h1.w + b1.w};
  uint16_t o[8];
#pragma unroll
  for (int i = 0; i < 8; i++) o[i] = f2bf(v[i] > 0.f ? v[i] : 0.f);
  uint4 ov; __builtin_memcpy(&ov, o, 16);
  *(uint4*)(msg + off) = ov;
}

// ---------------- h0 = segment_max(h_atom); write fp32 + bf16, both dirs (buf 0) --------
__global__ void k_h0(const float* __restrict__ h_atom, const int* __restrict__ start,
                     float* __restrict__ hf32, uint16_t* __restrict__ hbf) {
  int g = blockIdx.x, t = threadIdx.x;             // 256 threads * 4 cols
  int s = start[g], e = start[g + 1];
  float m[4] = {-INFINITY, -INFINITY, -INFINITY, -INFINITY};
  const float* base = h_atom + t * 4;
  for (int a = s; a < e; a++) {
    float4 v = *(const float4*)(base + (size_t)a * H);
    m[0] = fmaxf(m[0], v.x); m[1] = fmaxf(m[1], v.y);
    m[2] = fmaxf(m[2], v.z); m[3] = fmaxf(m[3], v.w);
  }
  if (s == e) { m[0] = m[1] = m[2] = m[3] = 0.f; }
#pragma unroll
  for (int i = 0; i < 4; i++) {
    int c = t * 4 + i;
    float mv = m[i];
    uint16_t bv = f2bf(mv);
    // layout: [(dir*2 + buf)][G][H]; buf 0 for both dirs
    hf32[(size_t)0 * G_ * H + (size_t)g * H + c] = mv;
    hf32[(size_t)2 * G_ * H + (size_t)g * H + c] = mv;
    hbf [(size_t)0 * G_ * H + (size_t)g * H + c] = bv;
    hbf [(size_t)2 * G_ * H + (size_t)g * H + c] = bv;
  }
}

// ---------------- xg = msg @ [Wf; Wb]^T  -> (N, 6144) bf16 ----------------
// 128x128 tile, BK=64, 4 waves 2x2, 16x16x32 MFMA, LDS-staged coalesced epilogue.
// (verbatim round-1 kernel — harness-verified)
__global__ __launch_bounds__(256) void k_gemm_xg(
    const uint16_t* __restrict__ A, const uint16_t* __restrict__ Wf,
    const uint16_t* __restrict__ Wb, uint16_t* __restrict__ C, int N) {
  __shared__ __align__(16) uint16_t SM[128 * 128];   // As(0..8191) Bs(8192..16383); reused as Cs
  uint16_t* As = SM;
  uint16_t* Bs = SM + 128 * 64;
  int bn = blockIdx.x, bm = blockIdx.y;            // bn 0..47, bm 0..N/128-1
  const uint16_t* B = (bn < 24) ? Wf : Wb;
  int brow = (bn < 24 ? bn : bn - 24) * 128;
  int tid = threadIdx.x, wid = tid >> 6, lane = tid & 63;
  int wm = wid >> 1, wn = wid & 1;
  floatx4 acc[4][4];
#pragma unroll
  for (int mi = 0; mi < 4; mi++)
#pragma unroll
    for (int ni = 0; ni < 4; ni++) acc[mi][ni] = (floatx4){0.f, 0.f, 0.f, 0.f};
  int arow = bm * 128;
  for (int kb = 0; kb < H; kb += 64) {
    uint4 av[4], bv[4];
#pragma unroll
    for (int p = 0; p < 4; p++) {                  // chunk c: row c>>3, k-off (c&7)*8
      int c = p * 256 + tid;
      av[p] = *(const uint4*)(A + (size_t)(arow + (c >> 3)) * H + kb + (c & 7) * 8);
      bv[p] = *(const uint4*)(B + (size_t)(brow + (c >> 3)) * H + kb + (c & 7) * 8);
    }
    __syncthreads();                               // prior iter's LDS reads done
#pragma unroll
    for (int p = 0; p < 4; p++) {
      int c = p * 256 + tid;
      *(uint4*)(As + (size_t)c * 8) = av[p];
      *(uint4*)(Bs + (size_t)c * 8) = bv[p];
    }
    __syncthreads();
#pragma unroll
    for (int ks = 0; ks < 2; ks++) {
      const uint16_t* ab = As + ((wm * 64 + (lane & 15)) * 64 + ks * 32 + (lane >> 4) * 8);
      const uint16_t* bb = Bs + ((wn * 64 + (lane & 15)) * 64 + ks * 32 + (lane >> 4) * 8);
      shortx8 af[4], bfr[4];
#pragma unroll
      for (int i = 0; i < 4; i++) {
        af[i]  = *(const shortx8*)(ab + i * 16 * 64);
        bfr[i] = *(const shortx8*)(bb + i * 16 * 64);
      }
#pragma unroll
      for (int mi = 0; mi < 4; mi++)
#pragma unroll
        for (int ni = 0; ni < 4; ni++)
          acc[mi][ni] = MFMA(af[mi], bfr[ni], acc[mi][ni]);
    }
  }
  __syncthreads();                                 // last MFMA LDS reads done; SM -> Cs
  int crow = wm * 64 + (lane >> 4) * 4;
  int ccol = wn * 64 + (lane & 15);
#pragma unroll
  for (int mi = 0; mi < 4; mi++)
#pragma unroll
    for (int ni = 0; ni < 4; ni++)
#pragma unroll
      for (int r = 0; r < 4; r++)
        SM[(crow + mi * 16 + r) * 128 + ccol + ni * 16] = f2bf(acc[mi][ni][r]);
  __syncthreads();
#pragma unroll
  for (int p = 0; p < 8; p++) {                    // 128 rows x 16 uint4/row, coalesced
    int c = p * 256 + tid;
    int row = c >> 4, col = (c & 15) * 8;
    *(uint4*)(C + (size_t)(arow + row) * 6144 + bn * 128 + col) =
        *(const uint4*)(SM + row * 128 + col);
  }
}

// ---------------- persistent fused GRU v3 ----------------
// Round-1-verified structure (256 WGs, WG = dir x 64 graphs x 32 cols, hf32/hbf state,
// identical gate phase + fence protocol) with four surgical fixes:
//  (1) grouped barriers: 8 counters (d x 64-graph range = exact dependency closure, 32 WGs
//      each, 128B apart) — round-1 serialized 256 cross-XCD RMWs on ONE line every step.
//  (2) load-early K-loop: kb+1 global loads issued before MFMA(kb) — latency hidden.
//  (3) LDS XOR swizzle (byte ^= (row&7)<<4) on write+read — kills 16-way ds_read_b128
//      conflict (SQ_LDS_BANK_CONFLICT was 3.1e8).
//  (4) step-top vectorized gate-input loads (xg as 3x uint4, h_old as 2x float4, biases
//      hoisted out of the l-loop) — round-1 issued 32 scalar loads at the step tail.
__global__ __launch_bounds__(256) void k_gru(
    const uint16_t* __restrict__ xg,
    const uint16_t* __restrict__ whf, const uint16_t* __restrict__ whb,
    const float* __restrict__ bihf, const float* __restrict__ bhhf,
    const float* __restrict__ bihb, const float* __restrict__ bhhb,
    float* __restrict__ hf32, uint16_t* __restrict__ hbf,
    const int* __restrict__ start, float* __restrict__ out,
    int* bar) {
  __shared__ __align__(16) uint16_t As[64 * 64];
  __shared__ __align__(16) uint16_t Bs[96 * 64];
  __shared__ float HG[64 * 97];                    // gate-triple exchange (stride 97)
  int b = blockIdx.x;
  int e = b & 7, hi = b >> 3;
  int d = e >> 2, jm = e & 3;                      // b&7 -> XCD slot: weight L2 affinity
  int jc = (hi & 7) * 4 + jm;                      // 0..31 (32-col chunk within H)
  int g0 = (hi >> 3) * 64;
  int grp = d * 4 + (hi >> 3);                     // sync group 0..7 (32 WGs each)
  const uint16_t* W = d ? whb : whf;
  int tid = threadIdx.x, wid = tid >> 6, lane = tid & 63;
  int wm = wid >> 1, wn = wid & 1;                 // waves 2x2 over (64 x 96) -> 32x48 tiles

  // gate-phase constants: thread owns (graph gl, 8 h-cols)
  int base = tid * 8;
  int gl = base >> 5, j0 = base & 31;
  int g = g0 + gl;
  int s = start[g], cnt = start[g + 1] - s;
  int col0 = jc * 32 + j0;
  const float* bih = d ? bihb : bihf;
  const float* bhh = d ? bhhb : bhhf;
  float br8[8], bz8[8], bni8[8], bnh8[8];
#pragma unroll
  for (int i = 0; i < 8; i++) {
    int c = col0 + i;
    br8[i] = bih[c] + bhh[c];
    bz8[i] = bih[H + c] + bhh[H + c];
    bni8[i] = bih[2 * H + c];
    bnh8[i] = bhh[2 * H + c];
  }

  // LDS write addressing (bytes), XOR-swizzled: pos = chunk*16 ^ ((row&7)<<4).
  // Read side uses key (lane&7)<<4 — valid because every fragment-row base
  // (wm*32, +16, wn*48, ni*16) is 0 mod 8, so row&7 == lane&7.
  int a_row[2], aw_off[2];
#pragma unroll
  for (int p = 0; p < 2; p++) {
    int c = p * 256 + tid, row = c >> 3;           // A rows 0..63
    a_row[p] = row;
    aw_off[p] = row * 128 + (((tid & 7) * 16) ^ ((row & 7) << 4));
  }
  int b_wrow[3], bw_off[3];
#pragma unroll
  for (int p = 0; p < 3; p++) {
    int c = p * 256 + tid, row = c >> 3;           // B rows 0..95 (r,z,n weight rows)
    b_wrow[p] = (row >> 5) * H + jc * 32 + (row & 31);
    bw_off[p] = row * 128 + (((tid & 7) * 16) ^ ((row & 7) << 4));
  }
  int xm = (lane & 7) << 4;
  int arow0 = (wm * 32 + (lane & 15)) * 128;
  int brow0 = (wn * 48 + (lane & 15)) * 128;
  int kchunk = (tid & 7) * 8;

  for (int l = 0; l < LPAD; l++) {
    int cur = l & 1;
    const uint16_t* hsrc = hbf + (size_t)(d * 2 + cur) * G_ * H;
    int t = d ? (LPAD - 1 - l) : l;
    bool active = (t < cnt);                       // padded steps: xt = b_ih (msg == 0)

    // step-top gate-input loads (latency hides under the whole K-loop)
    uint4 xr8 = {0, 0, 0, 0}, xz8 = {0, 0, 0, 0}, xn8 = {0, 0, 0, 0};
    if (active) {
      const uint16_t* xp = xg + (size_t)(s + t) * 6144 + (size_t)d * 3072 + col0;
      xr8 = *(const uint4*)xp;
      xz8 = *(const uint4*)(xp + H);
      xn8 = *(const uint4*)(xp + 2 * H);
    }
    const float* h_old = hf32 + ((size_t)(d * 2 + cur) * G_ + g) * H + col0;
    float4 ho0 = *(const float4*)h_old;
    float4 ho1 = *(const float4*)(h_old + 4);

    floatx4 acc[2][3];
#pragma unroll
    for (int mi = 0; mi < 2; mi++)
#pragma unroll
      for (int ni = 0; ni < 3; ni++) acc[mi][ni] = (floatx4){0.f, 0.f, 0.f, 0.f};

    // preload kb=0 into registers
    uint4 av[2], bv[3];
#pragma unroll
    for (int p = 0; p < 2; p++)
      av[p] = *(const uint4*)(hsrc + (size_t)(g0 + a_row[p]) * H + kchunk);
#pragma unroll
    for (int p = 0; p < 3; p++)
      bv[p] = *(const uint4*)(W + (size_t)b_wrow[p] * H + kchunk);

    for (int kb = 0; kb < 16; kb++) {
      __syncthreads();                             // prior iter's LDS reads done
#pragma unroll
      for (int p = 0; p < 2; p++) *(uint4*)((char*)As + aw_off[p]) = av[p];
#pragma unroll
      for (int p = 0; p < 3; p++) *(uint4*)((char*)Bs + bw_off[p]) = bv[p];
      __syncthreads();
      if (kb < 15) {                               // issue kb+1 loads BEFORE MFMA(kb)
        int ko = (kb + 1) * 64 + kchunk;
#pragma unroll
        for (int p = 0; p < 2; p++)
          av[p] = *(const uint4*)(hsrc + (size_t)(g0 + a_row[p]) * H + ko);
#pragma unroll
        for (int p = 0; p < 3; p++)
          bv[p] = *(const uint4*)(W + (size_t)b_wrow[p] * H + ko);
      }
#pragma unroll
      for (int ks = 0; ks < 2; ks++) {
        int o = (ks * 64 + (lane >> 4) * 16) ^ xm;
        shortx8 a0 = *(const shortx8*)((const char*)As + arow0 + o);
        shortx8 a1 = *(const shortx8*)((const char*)As + arow0 + 2048 + o);
#pragma unroll
        for (int ni = 0; ni < 3; ni++) {
          shortx8 bf_ = *(const shortx8*)((const char*)Bs + brow0 + ni * 2048 + o);
          acc[0][ni] = MFMA(a0, bf_, acc[0][ni]);
          acc[1][ni] = MFMA(a1, bf_, acc[1][ni]);
        }
      }
    }
    __syncthreads();                               // last MFMA ds_reads done before HG
    // spill hg (64x96) to LDS for the gate-triple exchange
#pragma unroll
    for (int mi = 0; mi < 2; mi++)
#pragma unroll
      for (int ni = 0; ni < 3; ni++) {
        int row0 = wm * 32 + mi * 16 + (lane >> 4) * 4;
        int col = wn * 48 + ni * 16 + (lane & 15);
#pragma unroll
        for (int r = 0; r < 4; r++) HG[(row0 + r) * 97 + col] = acc[mi][ni][r];
      }
    __syncthreads();

    // gates: 64*32 = 2048 h-elems, 8 per thread
    float hv[8] = {ho0.x, ho0.y, ho0.z, ho0.w, ho1.x, ho1.y, ho1.z, ho1.w};
    const uint16_t* xru = (const uint16_t*)&xr8;
    const uint16_t* xzu = (const uint16_t*)&xz8;
    const uint16_t* xnu = (const uint16_t*)&xn8;
    float o32[8]; uint16_t ob[8];
#pragma unroll
    for (int i = 0; i < 8; i++) {
      float hr = HG[gl * 97 + j0 + i];
      float hz = HG[gl * 97 + 32 + j0 + i];
      float hn = HG[gl * 97 + 64 + j0 + i];
      float r = sigmoid_(bf2f(xru[i]) + hr + br8[i]);
      float z = sigmoid_(bf2f(xzu[i]) + hz + bz8[i]);
      float n = tanh_(bf2f(xnu[i]) + bni8[i] + r * (hn + bnh8[i]));
      float hnew = (1.f - z) * n + z * hv[i];
      o32[i] = hnew;
      ob[i] = f2bf(hnew);
    }
    float* h_new32 = hf32 + ((size_t)(d * 2 + (cur ^ 1)) * G_ + g) * H + col0;
    uint16_t* h_newb = hbf + ((size_t)(d * 2 + (cur ^ 1)) * G_ + g) * H + col0;
    *(float4*)h_new32 = make_float4(o32[0], o32[1], o32[2], o32[3]);
    *(float4*)(h_new32 + 4) = make_float4(o32[4], o32[5], o32[6], o32[7]);
    uint4 obv; __builtin_memcpy(&obv, ob, 16);
    *(uint4*)h_newb = obv;
    if (active) {
      float* op = out + (size_t)(s + t) * 2048 + (size_t)d * H + col0;
      *(float4*)op = make_float4(o32[0], o32[1], o32[2], o32[3]);
      *(float4*)(op + 4) = make_float4(o32[4], o32[5], o32[6], o32[7]);
    }

    // ---- group barrier (32 WGs sharing (d, g-range)): h writes visible next step ----
    if (l + 1 < LPAD) {
      __syncthreads();                             // drains each wave's vmem (vmcnt 0)
      if (tid == 0) {
        __threadfence();                           // release: publish hbf to other XCDs
        __hip_atomic_fetch_add(&bar[grp * 32], 1, __ATOMIC_RELEASE, __HIP_MEMORY_SCOPE_AGENT);
        int tgt = (l + 1) * 32;
        while (__hip_atomic_load(&bar[grp * 32], __ATOMIC_RELAXED, __HIP_MEMORY_SCOPE_AGENT) < tgt)
          __builtin_amdgcn_s_sleep(2);
        __threadfence();                           // acquire
      }
      __syncthreads();
    }
  }
}

extern "C" void kernel_launch(void* const* d_in, const int* in_sizes, int n_in,
                              void* d_out, int out_size, void* d_ws, size_t ws_size,
                              hipStream_t stream) {
  const float* h_atom = (const float*)d_in[0];
  const int*   batch  = (const int*)d_in[1];
  const float* bias   = (const float*)d_in[2];
  const float* w_ih_f = (const float*)d_in[3];
  const float* w_hh_f = (const float*)d_in[4];
  const float* b_ih_f = (const float*)d_in[5];
  const float* b_hh_f = (const float*)d_in[6];
  const float* w_ih_b = (const float*)d_in[7];
  const float* w_hh_b = (const float*)d_in[8];
  const float* b_ih_b = (const float*)d_in[9];
  const float* b_hh_b = (const float*)d_in[10];
  int N = in_sizes[0] / H;                          // 16384
  float* out = (float*)d_out;

  const size_t W3 = (size_t)3 * H * H;              // 3.1M elems per weight
  char* ws = (char*)d_ws;
  uint16_t* msg  = (uint16_t*)ws;                           // N*H bf16
  uint16_t* xg   = (uint16_t*)(ws + (size_t)N * H * 2);     // N*6144 bf16
  char* p = ws + (size_t)N * H * 2 + (size_t)N * 6144 * 2;
  uint16_t* wihf = (uint16_t*)p; p += W3 * 2;
  uint16_t* wihb = (uint16_t*)p; p += W3 * 2;
  uint16_t* whhf = (uint16_t*)p; p += W3 * 2;
  uint16_t* whhb = (uint16_t*)p; p += W3 * 2;
  float*    hf32 = (float*)p;    p += (size_t)4 * G_ * H * 4;  // [dir][buf][G][H]
  uint16_t* hbf  = (uint16_t*)p; p += (size_t)4 * G_ * H * 2;
  int*      start = (int*)p;                                   // 257 ints
  int*      bar   = (int*)(p + 2048);                          // 8 groups x 32-int stride

  int wgrid = (int)(W3 / (256 * 8));                // 1536
  k_f2b<<<wgrid, 256, 0, stream>>>(w_ih_f, wihf);
  k_f2b<<<wgrid, 256, 0, stream>>>(w_ih_b, wihb);
  k_f2b<<<wgrid, 256, 0, stream>>>(w_hh_f, whhf);
  k_f2b<<<wgrid, 256, 0, stream>>>(w_hh_b, whhb);
  k_setup<<<1, 512, 0, stream>>>(batch, N, start, bar);
  k_msg<<<N, 128, 0, stream>>>(h_atom, bias, msg);
  k_h0<<<G_, 256, 0, stream>>>(h_atom, start, hf32, hbf);
  k_gemm_xg<<<dim3(48, N / 128), 256, 0, stream>>>(msg, wihf, wihb, xg, N);

  void* ka[] = {(void*)&xg, (void*)&whhf, (void*)&whhb,
                (void*)&b_ih_f, (void*)&b_hh_f, (void*)&b_ih_b, (void*)&b_hh_b,
                (void*)&hf32, (void*)&hbf, (void*)&start, (void*)&out, (void*)&bar};
  hipLaunchCooperativeKernel(k_gru, dim3(G_), dim3(256), ka, 0, stream);
}

// Round 4
// 6696.882 us; speedup vs baseline: 1.3254x; 1.1103x over previous
//
#include <hip/hip_runtime.h>
#include <stdint.h>

#define H 1024
#define G_ 256
#define LPAD 128

typedef float  floatx4 __attribute__((ext_vector_type(4)));
typedef short  shortx8 __attribute__((ext_vector_type(8)));
typedef uint16_t u16x4 __attribute__((ext_vector_type(4)));

#define MFMA(a, b, c) __builtin_amdgcn_mfma_f32_16x16x32_bf16((a), (b), (c), 0, 0, 0)

__device__ __forceinline__ uint16_t f2bf(float f) {
  union { float f; uint32_t i; } v; v.f = f;
  uint32_t r = (v.i + 0x7FFFu + ((v.i >> 16) & 1u)) >> 16;
  return (uint16_t)r;
}
__device__ __forceinline__ float bf2f(uint16_t u) {
  union { uint32_t i; float f; } v; v.i = ((uint32_t)u) << 16; return v.f;
}
__device__ __forceinline__ float sigmoid_(float x) { return 1.f / (1.f + __expf(-x)); }
__device__ __forceinline__ float tanh_(float x) {
  float ax = fabsf(x);
  float e = __expf(2.f * ax);          // overflow -> inf -> t = 1 (correct limit)
  float t = 1.f - 2.f / (e + 1.f);
  return x >= 0.f ? t : -t;
}

// ---------------- fp32 -> bf16 cast, 8 elems/thread ----------------
__global__ void k_f2b(const float* __restrict__ src, uint16_t* __restrict__ dst) {
  size_t i = ((size_t)blockIdx.x * blockDim.x + threadIdx.x) * 8;
  float4 a = *(const float4*)(src + i);
  float4 b = *(const float4*)(src + i + 4);
  uint16_t o[8] = {f2bf(a.x), f2bf(a.y), f2bf(a.z), f2bf(a.w),
                   f2bf(b.x), f2bf(b.y), f2bf(b.z), f2bf(b.w)};
  uint4 ov; __builtin_memcpy(&ov, o, 16);
  *(uint4*)(dst + i) = ov;
}

// ---------------- setup: start[g] via binary search; zero group barriers ----------------
__global__ void k_setup(const int* __restrict__ batch, int N, int* __restrict__ start,
                        int* __restrict__ bar) {
  int g = threadIdx.x;
  if (g < 512) bar[g] = 0;                         // 8 groups x 32-int stride (+ slack)
  if (g > G_) return;
  int lo = 0, hi = N;
  while (lo < hi) { int mid = (lo + hi) >> 1; if (batch[mid] < g) lo = mid + 1; else hi = mid; }
  start[g] = lo;
}

// ---------------- message = relu(h_atom + bias) -> bf16 ----------------
__global__ void k_msg(const float* __restrict__ h_atom, const float* __restrict__ bias,
                      uint16_t* __restrict__ msg) {
  int row = blockIdx.x, t = threadIdx.x;           // 128 threads * 8 elems
  size_t off = (size_t)row * H + t * 8;
  float4 h0 = *(const float4*)(h_atom + off);
  float4 h1 = *(const float4*)(h_atom + off + 4);
  float4 b0 = *(const float4*)(bias + t * 8);
  float4 b1 = *(const float4*)(bias + t * 8 + 4);
  float v[8] = {h0.x + b0.x, h0.y + b0.y, h0.z + b0.z, h0.w + b0.w,
                h1.x + b1.x, h1.y + b1.y, h1.z + b1.z, h1.w + b1.w};
  uint16_t o[8];
#pragma unroll
  for (int i = 0; i < 8; i++) o[i] = f2bf(v[i] > 0.f ? v[i] : 0.f);
  uint4 ov; __builtin_memcpy(&ov, o, 16);
  *(uint4*)(msg + off) = ov;
}

// ---------------- h0 = segment_max(h_atom); write fp32 + bf16, both dirs (buf 0) --------
__global__ void k_h0(const float* __restrict__ h_atom, const int* __restrict__ start,
                     float* __restrict__ hf32, uint16_t* __restrict__ hbf) {
  int g = blockIdx.x, t = threadIdx.x;             // 256 threads * 4 cols
  int s = start[g], e = start[g + 1];
  float m[4] = {-INFINITY, -INFINITY, -INFINITY, -INFINITY};
  const float* base = h_atom + t * 4;
  for (int a = s; a < e; a++) {
    float4 v = *(const float4*)(base + (size_t)a * H);
    m[0] = fmaxf(m[0], v.x); m[1] = fmaxf(m[1], v.y);
    m[2] = fmaxf(m[2], v.z); m[3] = fmaxf(m[3], v.w);
  }
  if (s == e) { m[0] = m[1] = m[2] = m[3] = 0.f; }
#pragma unroll
  for (int i = 0; i < 4; i++) {
    int c = t * 4 + i;
    float mv = m[i];
    uint16_t bv = f2bf(mv);
    // layout: [(dir*2 + buf)][G][H]; buf 0 for both dirs
    hf32[(size_t)0 * G_ * H + (size_t)g * H + c] = mv;
    hf32[(size_t)2 * G_ * H + (size_t)g * H + c] = mv;
    hbf [(size_t)0 * G_ * H + (size_t)g * H + c] = bv;
    hbf [(size_t)2 * G_ * H + (size_t)g * H + c] = bv;
  }
}

// ---------------- xg = msg @ [Wf; Wb]^T  -> (N, 6144) bf16 ----------------
// 128x128 tile, BK=64, 4 waves 2x2, 16x16x32 MFMA, LDS-staged coalesced epilogue.
// (verbatim round-1 kernel — harness-verified)
__global__ __launch_bounds__(256) void k_gemm_xg(
    const uint16_t* __restrict__ A, const uint16_t* __restrict__ Wf,
    const uint16_t* __restrict__ Wb, uint16_t* __restrict__ C, int N) {
  __shared__ __align__(16) uint16_t SM[128 * 128];   // As(0..8191) Bs(8192..16383); reused as Cs
  uint16_t* As = SM;
  uint16_t* Bs = SM + 128 * 64;
  int bn = blockIdx.x, bm = blockIdx.y;            // bn 0..47, bm 0..N/128-1
  const uint16_t* B = (bn < 24) ? Wf : Wb;
  int brow = (bn < 24 ? bn : bn - 24) * 128;
  int tid = threadIdx.x, wid = tid >> 6, lane = tid & 63;
  int wm = wid >> 1, wn = wid & 1;
  floatx4 acc[4][4];
#pragma unroll
  for (int mi = 0; mi < 4; mi++)
#pragma unroll
    for (int ni = 0; ni < 4; ni++) acc[mi][ni] = (floatx4){0.f, 0.f, 0.f, 0.f};
  int arow = bm * 128;
  for (int kb = 0; kb < H; kb += 64) {
    uint4 av[4], bv[4];
#pragma unroll
    for (int p = 0; p < 4; p++) {                  // chunk c: row c>>3, k-off (c&7)*8
      int c = p * 256 + tid;
      av[p] = *(const uint4*)(A + (size_t)(arow + (c >> 3)) * H + kb + (c & 7) * 8);
      bv[p] = *(const uint4*)(B + (size_t)(brow + (c >> 3)) * H + kb + (c & 7) * 8);
    }
    __syncthreads();                               // prior iter's LDS reads done
#pragma unroll
    for (int p = 0; p < 4; p++) {
      int c = p * 256 + tid;
      *(uint4*)(As + (size_t)c * 8) = av[p];
      *(uint4*)(Bs + (size_t)c * 8) = bv[p];
    }
    __syncthreads();
#pragma unroll
    for (int ks = 0; ks < 2; ks++) {
      const uint16_t* ab = As + ((wm * 64 + (lane & 15)) * 64 + ks * 32 + (lane >> 4) * 8);
      const uint16_t* bb = Bs + ((wn * 64 + (lane & 15)) * 64 + ks * 32 + (lane >> 4) * 8);
      shortx8 af[4], bfr[4];
#pragma unroll
      for (int i = 0; i < 4; i++) {
        af[i]  = *(const shortx8*)(ab + i * 16 * 64);
        bfr[i] = *(const shortx8*)(bb + i * 16 * 64);
      }
#pragma unroll
      for (int mi = 0; mi < 4; mi++)
#pragma unroll
        for (int ni = 0; ni < 4; ni++)
          acc[mi][ni] = MFMA(af[mi], bfr[ni], acc[mi][ni]);
    }
  }
  __syncthreads();                                 // last MFMA LDS reads done; SM -> Cs
  int crow = wm * 64 + (lane >> 4) * 4;
  int ccol = wn * 64 + (lane & 15);
#pragma unroll
  for (int mi = 0; mi < 4; mi++)
#pragma unroll
    for (int ni = 0; ni < 4; ni++)
#pragma unroll
      for (int r = 0; r < 4; r++)
        SM[(crow + mi * 16 + r) * 128 + ccol + ni * 16] = f2bf(acc[mi][ni][r]);
  __syncthreads();
#pragma unroll
  for (int p = 0; p < 8; p++) {                    // 128 rows x 16 uint4/row, coalesced
    int c = p * 256 + tid;
    int row = c >> 4, col = (c & 15) * 8;
    *(uint4*)(C + (size_t)(arow + row) * 6144 + bn * 128 + col) =
        *(const uint4*)(SM + row * 128 + col);
  }
}

// ---------------- persistent fused GRU v4 ----------------
// V3-verified skeleton (partition over (dir, g-range, jc), gate math, fence protocol)
// with four traced changes:
//  (1) 512-thread WGs, split-K: waves 0-3 own k[0,512), waves 4-7 own k[512,1024);
//      each half runs V3's exact 2x2-wave 64x96 micro-kernel on its own As/Bs half.
//      8 waves/CU (2/SIMD) -> latencies overlap; serial chain 16 -> 8 double-barrier iters.
//  (2) LDS union: HG[2][64][97] f32 aliases As/Bs (disjoint in time via existing barriers).
//  (3) h fp32 state in registers (thread<->(g,4 cols) static across l); hf32 is init-only.
//  (4) bid remap gid=bid&7, jc=bid>>3: sync group's 32 WGs land on one XCD (round-robin
//      dispatch heuristic) -> barrier line + hbf lines XCD-local; agent fences unchanged.
__global__ __launch_bounds__(512) void k_gru(
    const uint16_t* __restrict__ xg,
    const uint16_t* __restrict__ whf, const uint16_t* __restrict__ whb,
    const float* __restrict__ bihf, const float* __restrict__ bhhf,
    const float* __restrict__ bihb, const float* __restrict__ bhhb,
    const float* __restrict__ hf32, uint16_t* __restrict__ hbf,
    const int* __restrict__ start, float* __restrict__ out,
    int* bar) {
  // As: bytes [0,16384) = 2 halves x (64 rows x 128 B); Bs: [16384,40960) = 2 x (96 x 128 B)
  // HG: floats, kh*6208 + row*97 + col, bytes [0,49664) — aliases As/Bs (time-disjoint)
  __shared__ __align__(16) char SMEM[49664];
  char* AsB = SMEM;
  char* BsB = SMEM + 16384;
  float* HGf = (float*)SMEM;

  int b = blockIdx.x;
  int gid = b & 7;                                 // sync group == XCD slot
  int d = gid >> 2, grange = gid & 3;
  int jc = b >> 3;                                 // 0..31: 32-col chunk of H
  int g0 = grange * 64;
  const uint16_t* W = d ? whb : whf;
  int tid = threadIdx.x, lane = tid & 63, wid = tid >> 6;
  int kh = wid >> 2;                               // K-half: 0 -> k<512, 1 -> k>=512
  int wq = wid & 3, wm = wq >> 1, wn = wq & 1;     // 2x2 waves over 64x96 within half
  int th = tid & 255;                              // staging id within half-group

  // gate-phase constants: thread owns (graph gl, 4 h-cols)
  int gl = tid >> 3, j0 = (tid & 7) * 4;
  int g = g0 + gl;
  int s = start[g], cnt = start[g + 1] - s;
  int col0 = jc * 32 + j0;
  const float* bih = d ? bihb : bihf;
  const float* bhh = d ? bhhb : bhhf;
  float br4[4], bz4[4], bni4[4], bnh4[4];
#pragma unroll
  for (int i = 0; i < 4; i++) {
    int c = col0 + i;
    br4[i] = bih[c] + bhh[c];
    bz4[i] = bih[H + c] + bhh[H + c];
    bni4[i] = bih[2 * H + c];
    bnh4[i] = bhh[2 * H + c];
  }
  float hreg[4];                                   // persistent fp32 h (own (g, cols))
  {
    float4 h4 = *(const float4*)(hf32 + ((size_t)(d * 2) * G_ + g) * H + col0);
    hreg[0] = h4.x; hreg[1] = h4.y; hreg[2] = h4.z; hreg[3] = h4.w;
  }

  // staging addressing (bytes), XOR swizzle: pos = chunk*16 ^ ((row&7)<<4)
  int a_row[2], aw_off[2];
#pragma unroll
  for (int p = 0; p < 2; p++) {
    int c = p * 256 + th, row = c >> 3;            // A rows 0..63
    a_row[p] = row;
    aw_off[p] = kh * 8192 + row * 128 + (((th & 7) * 16) ^ ((row & 7) << 4));
  }
  int b_wrow[3], bw_off[3];
#pragma unroll
  for (int p = 0; p < 3; p++) {
    int c = p * 256 + th, row = c >> 3;            // B rows 0..95 (r,z,n triples)
    b_wrow[p] = (row >> 5) * H + jc * 32 + (row & 31);
    bw_off[p] = kh * 12288 + row * 128 + (((th & 7) * 16) ^ ((row & 7) << 4));
  }
  int kchunk = (th & 7) * 8;                       // staged k-subchunk within 64
  int xm = (lane & 7) << 4;                        // read-side swizzle key (row&7==lane&7)
  int arow0 = kh * 8192 + (wm * 32 + (lane & 15)) * 128;
  int brow0 = kh * 12288 + (wn * 48 + (lane & 15)) * 128;

  for (int l = 0; l < LPAD; l++) {
    int cur = l & 1;
    const uint16_t* hsrc = hbf + (size_t)(d * 2 + cur) * G_ * H;
    int t = d ? (LPAD - 1 - l) : l;
    bool active = (t < cnt);                       // padded steps: xt = b_ih (msg == 0)

    // step-top gate-input loads (latency hides under the whole K-loop)
    u16x4 xr4 = {0, 0, 0, 0}, xz4 = {0, 0, 0, 0}, xn4 = {0, 0, 0, 0};
    if (active) {
      const uint16_t* xp = xg + (size_t)(s + t) * 6144 + (size_t)d * 3072 + col0;
      xr4 = *(const u16x4*)xp;
      xz4 = *(const u16x4*)(xp + H);
      xn4 = *(const u16x4*)(xp + 2 * H);
    }

    floatx4 acc[2][3];
#pragma unroll
    for (int mi = 0; mi < 2; mi++)
#pragma unroll
      for (int ni = 0; ni < 3; ni++) acc[mi][ni] = (floatx4){0.f, 0.f, 0.f, 0.f};

    // preload kb=0 of this thread's K-half
    uint4 av[2], bv[3];
    int kbase = kh * 512 + kchunk;
#pragma unroll
    for (int p = 0; p < 2; p++)
      av[p] = *(const uint4*)(hsrc + (size_t)(g0 + a_row[p]) * H + kbase);
#pragma unroll
    for (int p = 0; p < 3; p++)
      bv[p] = *(const uint4*)(W + (size_t)b_wrow[p] * H + kbase);

    for (int kb = 0; kb < 8; kb++) {
      __syncthreads();                             // prior LDS reads done (or HG of prev step)
#pragma unroll
      for (int p = 0; p < 2; p++) *(uint4*)(AsB + aw_off[p]) = av[p];
#pragma unroll
      for (int p = 0; p < 3; p++) *(uint4*)(BsB + bw_off[p]) = bv[p];
      __syncthreads();
      if (kb < 7) {                                // issue kb+1 loads BEFORE MFMA(kb)
        int ko = kh * 512 + (kb + 1) * 64 + kchunk;
#pragma unroll
        for (int p = 0; p < 2; p++)
          av[p] = *(const uint4*)(hsrc + (size_t)(g0 + a_row[p]) * H + ko);
#pragma unroll
        for (int p = 0; p < 3; p++)
          bv[p] = *(const uint4*)(W + (size_t)b_wrow[p] * H + ko);
      }
#pragma unroll
      for (int ks = 0; ks < 2; ks++) {
        int o = (ks * 64 + (lane >> 4) * 16) ^ xm;
        shortx8 a0 = *(const shortx8*)(AsB + arow0 + o);
        shortx8 a1 = *(const shortx8*)(AsB + arow0 + 2048 + o);
#pragma unroll
        for (int ni = 0; ni < 3; ni++) {
          shortx8 bf_ = *(const shortx8*)(BsB + brow0 + ni * 2048 + o);
          acc[0][ni] = MFMA(a0, bf_, acc[0][ni]);
          acc[1][ni] = MFMA(a1, bf_, acc[1][ni]);
        }
      }
    }
    __syncthreads();                               // all MFMA ds_reads done; SMEM -> HG
    // spill hg halves (64x96 each) for the gate-triple exchange + split-K reduction
#pragma unroll
    for (int mi = 0; mi < 2; mi++)
#pragma unroll
      for (int ni = 0; ni < 3; ni++) {
        int row0 = wm * 32 + mi * 16 + (lane >> 4) * 4;
        int col = wn * 48 + ni * 16 + (lane & 15);
#pragma unroll
        for (int r = 0; r < 4; r++)
          HGf[kh * 6208 + (row0 + r) * 97 + col] = acc[mi][ni][r];
      }
    __syncthreads();

    // gates: 64*32 = 2048 h-elems, 4 per thread; h in registers
    const uint16_t* xru = (const uint16_t*)&xr4;
    const uint16_t* xzu = (const uint16_t*)&xz4;
    const uint16_t* xnu = (const uint16_t*)&xn4;
    uint16_t ob[4]; floatx4 ov;
#pragma unroll
    for (int i = 0; i < 4; i++) {
      int hx = gl * 97 + j0 + i;
      float hr = HGf[hx] + HGf[6208 + hx];
      float hz = HGf[hx + 32] + HGf[6208 + hx + 32];
      float hn = HGf[hx + 64] + HGf[6208 + hx + 64];
      float r = sigmoid_(bf2f(xru[i]) + hr + br4[i]);
      float z = sigmoid_(bf2f(xzu[i]) + hz + bz4[i]);
      float n = tanh_(bf2f(xnu[i]) + bni4[i] + r * (hn + bnh4[i]));
      float hnew = (1.f - z) * n + z * hreg[i];
      hreg[i] = hnew;
      ob[i] = f2bf(hnew);
      ov[i] = hnew;
    }
    uint16_t* hb = hbf + ((size_t)(d * 2 + (cur ^ 1)) * G_ + g) * H + col0;
    u16x4 obv; __builtin_memcpy(&obv, ob, 8);
    *(u16x4*)hb = obv;
    if (active) {
      float* op = out + (size_t)(s + t) * 2048 + (size_t)d * H + col0;
      *(floatx4*)op = ov;
    }

    // ---- group barrier (32 WGs sharing (d, g-range)): hbf visible next step ----
    if (l + 1 < LPAD) {
      __syncthreads();                             // drains each wave's vmem (vmcnt 0)
      if (tid == 0) {
        __threadfence();                           // release: publish hbf
        __hip_atomic_fetch_add(&bar[gid * 32], 1, __ATOMIC_RELEASE, __HIP_MEMORY_SCOPE_AGENT);
        int tgt = (l + 1) * 32;
        while (__hip_atomic_load(&bar[gid * 32], __ATOMIC_RELAXED, __HIP_MEMORY_SCOPE_AGENT) < tgt)
          __builtin_amdgcn_s_sleep(2);
        __threadfence();                           // acquire
      }
      __syncthreads();
    }
  }
}

extern "C" void kernel_launch(void* const* d_in, const int* in_sizes, int n_in,
                              void* d_out, int out_size, void* d_ws, size_t ws_size,
                              hipStream_t stream) {
  const float* h_atom = (const float*)d_in[0];
  const int*   batch  = (const int*)d_in[1];
  const float* bias   = (const float*)d_in[2];
  const float* w_ih_f = (const float*)d_in[3];
  const float* w_hh_f = (const float*)d_in[4];
  const float* b_ih_f = (const float*)d_in[5];
  const float* b_hh_f = (const float*)d_in[6];
  const float* w_ih_b = (const float*)d_in[7];
  const float* w_hh_b = (const float*)d_in[8];
  const float* b_ih_b = (const float*)d_in[9];
  const float* b_hh_b = (const float*)d_in[10];
  int N = in_sizes[0] / H;                          // 16384
  float* out = (float*)d_out;

  const size_t W3 = (size_t)3 * H * H;              // 3.1M elems per weight
  char* ws = (char*)d_ws;
  uint16_t* msg  = (uint16_t*)ws;                           // N*H bf16
  uint16_t* xg   = (uint16_t*)(ws + (size_t)N * H * 2);     // N*6144 bf16
  char* p = ws + (size_t)N * H * 2 + (size_t)N * 6144 * 2;
  uint16_t* wihf = (uint16_t*)p; p += W3 * 2;
  uint16_t* wihb = (uint16_t*)p; p += W3 * 2;
  uint16_t* whhf = (uint16_t*)p; p += W3 * 2;
  uint16_t* whhb = (uint16_t*)p; p += W3 * 2;
  float*    hf32 = (float*)p;    p += (size_t)4 * G_ * H * 4;  // [dir][buf][G][H] (init only)
  uint16_t* hbf  = (uint16_t*)p; p += (size_t)4 * G_ * H * 2;
  int*      start = (int*)p;                                   // 257 ints
  int*      bar   = (int*)(p + 2048);                          // 8 groups x 32-int stride

  int wgrid = (int)(W3 / (256 * 8));                // 1536
  k_f2b<<<wgrid, 256, 0, stream>>>(w_ih_f, wihf);
  k_f2b<<<wgrid, 256, 0, stream>>>(w_ih_b, wihb);
  k_f2b<<<wgrid, 256, 0, stream>>>(w_hh_f, whhf);
  k_f2b<<<wgrid, 256, 0, stream>>>(w_hh_b, whhb);
  k_setup<<<1, 512, 0, stream>>>(batch, N, start, bar);
  k_msg<<<N, 128, 0, stream>>>(h_atom, bias, msg);
  k_h0<<<G_, 256, 0, stream>>>(h_atom, start, hf32, hbf);
  k_gemm_xg<<<dim3(48, N / 128), 256, 0, stream>>>(msg, wihf, wihb, xg, N);

  void* ka[] = {(void*)&xg, (void*)&whhf, (void*)&whhb,
                (void*)&b_ih_f, (void*)&b_hh_f, (void*)&b_ih_b, (void*)&b_hh_b,
                (void*)&hf32, (void*)&hbf, (void*)&start, (void*)&out, (void*)&bar};
  hipLaunchCooperativeKernel(k_gru, dim3(G_), dim3(512), ka, 0, stream);
}